// Round 5
// baseline (79.325 us; speedup 1.0000x reference)
//
#include <hip/hip_runtime.h>
#include <hip/hip_bf16.h>

#define MARGIN_F 0.25f

// Problem constants (fixed by setup_inputs).
#define B_ANCH 2048
#define P_POS  2048
#define N_NEG  32768   // 2048 * 16
#define DDIM   128

typedef __attribute__((ext_vector_type(8))) short bf16x8;   // 8 bf16 = 4 VGPRs
typedef __attribute__((ext_vector_type(4))) float f32x4;

__device__ __forceinline__ short f2bf(float x) {
    __hip_bfloat16 h = __float2bfloat16(x);
    return *reinterpret_cast<short*>(&h);
}

// ---------------------------------------------------------------------------
// Prep: f32 -> bf16 in FRAGMENT-MAJOR layout + fp32 row norms + accumulator
// and counter init. Anchor fragments are stored PRE-SCALED by -2 (exact in
// bf16) so the MFMA directly computes ny - 2*a.y when C is seeded with ny.
// Packed layout: for 16-row tile T, k-step s (32 dims), lane l
// (lm=l&15 row-in-tile, lk=l>>4 dim-group):
//   packed[((T*4+s)*64 + l)*8 + j] = bf16( scl * src[(T*16+lm)*128 + s*32+lk*8+j] )
// ---------------------------------------------------------------------------
__global__ __launch_bounds__(256) void prep_kernel(
    const float* __restrict__ anchor, const float* __restrict__ positive,
    const float* __restrict__ negative,
    short* __restrict__ pA, short* __restrict__ pP, short* __restrict__ pN,
    float* __restrict__ nA, float* __restrict__ nP, float* __restrict__ nN,
    unsigned* __restrict__ dposBits, unsigned* __restrict__ dnegBits,
    unsigned* __restrict__ doneCnt)
{
    const int tile = blockIdx.x * 4 + (threadIdx.x >> 6);   // global 16-row tile
    const int lane = threadIdx.x & 63;
    const int lm = lane & 15, lk = lane >> 4;

    const float* src; short* dst; float* nrm; int t; float scl;
    const int TA = B_ANCH / 16, TP = P_POS / 16;
    if (tile < TA) {
        src = anchor; dst = pA; nrm = nA; t = tile; scl = -2.f;
        if (lm == lane) dposBits[tile * 16 + lm] = 0u;      // lanes 0..15
    } else if (tile < TA + TP) {
        src = positive; dst = pP; nrm = nP; t = tile - TA; scl = 1.f;
    } else {
        src = negative; dst = pN; nrm = nN; t = tile - TA - TP; scl = 1.f;
    }
    if (blockIdx.x == 0 && threadIdx.x == 0) {
        *dnegBits = 0x7F800000u;  // +inf
        *doneCnt  = 0u;
    }

    const int row = t * 16 + lm;
    float ss = 0.f;
    #pragma unroll
    for (int s = 0; s < 4; ++s) {
        const float* sp = src + (size_t)row * DDIM + s * 32 + lk * 8;
        float4 v0 = *(const float4*)sp;
        float4 v1 = *(const float4*)(sp + 4);
        ss += v0.x*v0.x + v0.y*v0.y + v0.z*v0.z + v0.w*v0.w
            + v1.x*v1.x + v1.y*v1.y + v1.z*v1.z + v1.w*v1.w;
        bf16x8 o;
        o[0]=f2bf(scl*v0.x); o[1]=f2bf(scl*v0.y); o[2]=f2bf(scl*v0.z); o[3]=f2bf(scl*v0.w);
        o[4]=f2bf(scl*v1.x); o[5]=f2bf(scl*v1.y); o[6]=f2bf(scl*v1.z); o[7]=f2bf(scl*v1.w);
        *(bf16x8*)(dst + ((size_t)(t * 4 + s) * 64 + lane) * 8) = o;
    }
    ss += __shfl_xor(ss, 16);
    ss += __shfl_xor(ss, 32);
    if (lk == 0) nrm[row] = ss;
}

// ---------------------------------------------------------------------------
// Distance + reduce tile body. 128-row block tile, 4 waves (2x2); each wave
// owns 64 rows x 64 cols per column group, loops over G = CT*4 16-col groups.
// b[3][4]: depth-2 rolling B prefetch. acc[2][4]: double-buffered accumulator
// so the fmin/fmax epilogue of group g-1 overlaps the MFMA issue of group g
// (no WAR serialization). MFMA C seeded with ny; A pre-scaled by -2 => the
// MFMA output IS (ny - 2 a.y). |a|^2 added once at the end (clamp commutes
// with min/max). All indices compile-time after full unroll.
// MODE 0: per-row max -> atomicMax(dposBits[row]); MODE 1: global min ->
// one atomicMin(dnegBits) per block.
// ---------------------------------------------------------------------------
template<int MODE, int CT>
__device__ __forceinline__ void dist_tile(
    const bf16x8* __restrict__ Af, const bf16x8* __restrict__ Yf,
    const float* __restrict__ nA, const float* __restrict__ nY,
    int by, int bx,
    unsigned* __restrict__ dposBits, unsigned* __restrict__ dnegBits)
{
    const int wid  = threadIdx.x >> 6;
    const int lane = threadIdx.x & 63;
    const int lm = lane & 15, lk = lane >> 4;
    const int wr = wid >> 1, wc = wid & 1;
    const int rt0 = by * 8 + wr * 4;          // first 16-row A tile of this wave

    // A fragments (pre-scaled by -2): 64 rows x 128 dims, resident throughout.
    bf16x8 a[4][4];
    #pragma unroll
    for (int m = 0; m < 4; ++m)
        #pragma unroll
        for (int s = 0; s < 4; ++s)
            a[m][s] = Af[(size_t)((rt0 + m) * 4 + s) * 64 + lane];

    float red[4][4];
    #pragma unroll
    for (int m = 0; m < 4; ++m)
        #pragma unroll
        for (int r = 0; r < 4; ++r)
            red[m][r] = (MODE == 0) ? -3.4e38f : 3.4e38f;

    constexpr int G = CT * 4;

    bf16x8 b[3][4];
    float nyv[3];
    #pragma unroll
    for (int p = 0; p < 2 && p < G; ++p) {
        const int ctile = (bx * CT + (p >> 2)) * 8 + wc * 4 + (p & 3);
        #pragma unroll
        for (int s = 0; s < 4; ++s)
            b[p][s] = Yf[(size_t)(ctile * 4 + s) * 64 + lane];
        nyv[p] = nY[ctile * 16 + lm];
    }

    f32x4 acc[2][4];

    #pragma unroll
    for (int g = 0; g < G; ++g) {
        const int cb = g % 3;      // current b buffer   (static after unroll)
        const int ab = g & 1;      // current acc buffer (static after unroll)
        // prefetch group g+2
        if (g + 2 < G) {
            const int ctile = (bx * CT + ((g + 2) >> 2)) * 8 + wc * 4 + ((g + 2) & 3);
            #pragma unroll
            for (int s = 0; s < 4; ++s)
                b[(g + 2) % 3][s] = Yf[(size_t)(ctile * 4 + s) * 64 + lane];
            nyv[(g + 2) % 3] = nY[ctile * 16 + lm];
        }
        // seed C with ny (off the dependent path), then MFMA
        const float ny = nyv[cb];
        #pragma unroll
        for (int m = 0; m < 4; ++m) acc[ab][m] = f32x4{ny, ny, ny, ny};
        #pragma unroll
        for (int s = 0; s < 4; ++s)
            #pragma unroll
            for (int m = 0; m < 4; ++m)
                acc[ab][m] = __builtin_amdgcn_mfma_f32_16x16x32_bf16(a[m][s], b[cb][s], acc[ab][m], 0, 0, 0);
        // epilogue of the PREVIOUS group overlaps this group's MFMAs
        if (g > 0) {
            #pragma unroll
            for (int m = 0; m < 4; ++m)
                #pragma unroll
                for (int r = 0; r < 4; ++r)
                    red[m][r] = (MODE == 0) ? fmaxf(red[m][r], acc[ab ^ 1][m][r])
                                            : fminf(red[m][r], acc[ab ^ 1][m][r]);
        }
    }
    // drain: epilogue of the last group
    {
        const int ab = (G - 1) & 1;
        #pragma unroll
        for (int m = 0; m < 4; ++m)
            #pragma unroll
            for (int r = 0; r < 4; ++r)
                red[m][r] = (MODE == 0) ? fmaxf(red[m][r], acc[ab][m][r])
                                        : fminf(red[m][r], acc[ab][m][r]);
    }

    float na[4][4];
    #pragma unroll
    for (int m = 0; m < 4; ++m)
        #pragma unroll
        for (int r = 0; r < 4; ++r)
            na[m][r] = nA[(rt0 + m) * 16 + 4 * lk + r];

    if (MODE == 0) {
        #pragma unroll
        for (int msk = 1; msk < 16; msk <<= 1)
            #pragma unroll
            for (int m = 0; m < 4; ++m)
                #pragma unroll
                for (int r = 0; r < 4; ++r)
                    red[m][r] = fmaxf(red[m][r], __shfl_xor(red[m][r], msk));
        if (lm == 0) {
            #pragma unroll
            for (int m = 0; m < 4; ++m)
                #pragma unroll
                for (int r = 0; r < 4; ++r) {
                    const float sq = fmaxf(na[m][r] + red[m][r], 0.f);
                    atomicMax(dposBits + ((rt0 + m) * 16 + 4 * lk + r),
                              __float_as_uint(sq));
                }
        }
    } else {
        float mn = 3.4e38f;
        #pragma unroll
        for (int m = 0; m < 4; ++m)
            #pragma unroll
            for (int r = 0; r < 4; ++r)
                mn = fminf(mn, na[m][r] + red[m][r]);
        mn = fmaxf(mn, 0.f);
        #pragma unroll
        for (int msk = 1; msk < 64; msk <<= 1) mn = fminf(mn, __shfl_xor(mn, msk));
        __shared__ float wmin[4];
        if (lane == 0) wmin[wid] = mn;
        __syncthreads();
        if (threadIdx.x == 0) {
            const float m2 = fminf(fminf(wmin[0], wmin[1]), fminf(wmin[2], wmin[3]));
            atomicMin(dnegBits, __float_as_uint(m2));
        }
    }
}

#define POS_BLOCKS ((P_POS / 128) * (B_ANCH / 128))            // 256
#define NEG_CT 8
#define NEG_BLOCKS ((N_NEG / (128 * NEG_CT)) * (B_ANCH / 128)) // 512
#define TOT_BLOCKS (POS_BLOCKS + NEG_BLOCKS)

__global__ __launch_bounds__(256, 2) void fused_dist_kernel(
    const short* __restrict__ pA, const short* __restrict__ pP,
    const short* __restrict__ pN,
    const float* __restrict__ nA, const float* __restrict__ nP,
    const float* __restrict__ nN,
    unsigned* __restrict__ dposBits, unsigned* __restrict__ dnegBits,
    unsigned* __restrict__ doneCnt, float* __restrict__ out)
{
    const int bid = blockIdx.x;
    if (bid < POS_BLOCKS) {
        // positives: short blocks first so they co-schedule with negatives
        dist_tile<0, 1>((const bf16x8*)pA, (const bf16x8*)pP, nA, nP,
                        bid >> 4, bid & 15, dposBits, dnegBits);
    } else {
        const int q = bid - POS_BLOCKS;
        dist_tile<1, NEG_CT>((const bf16x8*)pA, (const bf16x8*)pN, nA, nN,
                             q >> 5, q & 31, dposBits, dnegBits);
    }

    // ---- last-block finalize: mean(relu(sqrt(dpos) - sqrt(dneg) + margin))
    __threadfence();                       // make this block's atomics visible
    __shared__ unsigned lastFlag;
    if (threadIdx.x == 0)
        lastFlag = (atomicAdd(doneCnt, 1u) == TOT_BLOCKS - 1) ? 1u : 0u;
    __syncthreads();
    if (lastFlag) {
        __threadfence();                   // acquire side
        const float dneg = sqrtf(__uint_as_float(atomicAdd(dnegBits, 0u)));
        float s = 0.f;
        for (int i = threadIdx.x; i < B_ANCH; i += 256) {
            const float dp = sqrtf(__uint_as_float(atomicAdd(dposBits + i, 0u)));
            s += fmaxf(dp - dneg + MARGIN_F, 0.f);
        }
        #pragma unroll
        for (int m = 1; m < 64; m <<= 1) s += __shfl_xor(s, m);
        __shared__ float ws4[4];
        const int wid = threadIdx.x >> 6, lane = threadIdx.x & 63;
        if (lane == 0) ws4[wid] = s;
        __syncthreads();
        if (threadIdx.x == 0)
            out[0] = (ws4[0] + ws4[1] + ws4[2] + ws4[3]) * (1.f / (float)B_ANCH);
    }
}

// ---------------------------------------------------------------------------
extern "C" void kernel_launch(void* const* d_in, const int* in_sizes, int n_in,
                              void* d_out, int out_size, void* d_ws, size_t ws_size,
                              hipStream_t stream) {
    const float* anchor   = (const float*)d_in[0];
    const float* positive = (const float*)d_in[1];
    const float* negative = (const float*)d_in[2];
    float* out = (float*)d_out;

    char* ws = (char*)d_ws;
    size_t off = 0;
    auto alloc = [&](size_t bytes) { char* p = ws + off; off = (off + bytes + 255) & ~(size_t)255; return p; };

    short* pA = (short*)alloc((size_t)B_ANCH * DDIM * 2);
    short* pP = (short*)alloc((size_t)P_POS  * DDIM * 2);
    short* pN = (short*)alloc((size_t)N_NEG  * DDIM * 2);
    float* nA  = (float*)alloc((size_t)B_ANCH * 4);
    float* nP  = (float*)alloc((size_t)P_POS  * 4);
    float* nN  = (float*)alloc((size_t)N_NEG  * 4);
    unsigned* dposBits = (unsigned*)alloc((size_t)B_ANCH * 4);
    unsigned* dnegBits = (unsigned*)alloc(4);
    unsigned* doneCnt  = (unsigned*)alloc(4);

    // 1. prep: one wave per 16-row tile, 4 tiles per block
    const int totalTiles = (B_ANCH + P_POS + N_NEG) / 16;   // 2304
    prep_kernel<<<totalTiles / 4, 256, 0, stream>>>(
        anchor, positive, negative, pA, pP, pN, nA, nP, nN,
        dposBits, dnegBits, doneCnt);

    // 2. fused positives + negatives distance/reduce + last-block finalize
    fused_dist_kernel<<<TOT_BLOCKS, 256, 0, stream>>>(
        pA, pP, pN, nA, nP, nN, dposBits, dnegBits, doneCnt, out);
}

// Round 6
// 37.218 us; speedup vs baseline: 2.1313x; 2.1313x over previous
//
#include <hip/hip_runtime.h>
#include <hip/hip_bf16.h>

#define MARGIN_F 0.25f

// Problem constants (fixed by setup_inputs).
#define B_ANCH 2048
#define P_POS  2048
#define N_NEG  32768   // 2048 * 16
#define DDIM   128

typedef __attribute__((ext_vector_type(8))) short bf16x8;   // 8 bf16 = 4 VGPRs
typedef __attribute__((ext_vector_type(4))) float f32x4;

__device__ __forceinline__ short f2bf(float x) {
    __hip_bfloat16 h = __float2bfloat16(x);
    return *reinterpret_cast<short*>(&h);
}

// ---------------------------------------------------------------------------
// Prep: f32 -> bf16 in FRAGMENT-MAJOR layout + fp32 row norms + accumulator
// init. Anchor fragments stored PRE-SCALED by -2 (exact in bf16) so the MFMA
// directly computes ny - 2*a.y when C is seeded with ny.
// Packed layout: for 16-row tile T, k-step s (32 dims), lane l
// (lm=l&15 row-in-tile, lk=l>>4 dim-group):
//   packed[((T*4+s)*64 + l)*8 + j] = bf16( scl * src[(T*16+lm)*128 + s*32+lk*8+j] )
// ---------------------------------------------------------------------------
__global__ __launch_bounds__(256) void prep_kernel(
    const float* __restrict__ anchor, const float* __restrict__ positive,
    const float* __restrict__ negative,
    short* __restrict__ pA, short* __restrict__ pP, short* __restrict__ pN,
    float* __restrict__ nA, float* __restrict__ nP, float* __restrict__ nN,
    unsigned* __restrict__ dposBits, unsigned* __restrict__ dnegBits)
{
    const int tile = blockIdx.x * 4 + (threadIdx.x >> 6);   // global 16-row tile
    const int lane = threadIdx.x & 63;
    const int lm = lane & 15, lk = lane >> 4;

    const float* src; short* dst; float* nrm; int t; float scl;
    const int TA = B_ANCH / 16, TP = P_POS / 16;
    if (tile < TA) {
        src = anchor; dst = pA; nrm = nA; t = tile; scl = -2.f;
        if (lm == lane) dposBits[tile * 16 + lm] = 0u;      // lanes 0..15
    } else if (tile < TA + TP) {
        src = positive; dst = pP; nrm = nP; t = tile - TA; scl = 1.f;
    } else {
        src = negative; dst = pN; nrm = nN; t = tile - TA - TP; scl = 1.f;
    }
    if (blockIdx.x == 0 && threadIdx.x == 0) *dnegBits = 0x7F800000u;  // +inf

    const int row = t * 16 + lm;
    float ss = 0.f;
    #pragma unroll
    for (int s = 0; s < 4; ++s) {
        const float* sp = src + (size_t)row * DDIM + s * 32 + lk * 8;
        float4 v0 = *(const float4*)sp;
        float4 v1 = *(const float4*)(sp + 4);
        ss += v0.x*v0.x + v0.y*v0.y + v0.z*v0.z + v0.w*v0.w
            + v1.x*v1.x + v1.y*v1.y + v1.z*v1.z + v1.w*v1.w;
        bf16x8 o;
        o[0]=f2bf(scl*v0.x); o[1]=f2bf(scl*v0.y); o[2]=f2bf(scl*v0.z); o[3]=f2bf(scl*v0.w);
        o[4]=f2bf(scl*v1.x); o[5]=f2bf(scl*v1.y); o[6]=f2bf(scl*v1.z); o[7]=f2bf(scl*v1.w);
        *(bf16x8*)(dst + ((size_t)(t * 4 + s) * 64 + lane) * 8) = o;
    }
    ss += __shfl_xor(ss, 16);
    ss += __shfl_xor(ss, 32);
    if (lk == 0) nrm[row] = ss;
}

// ---------------------------------------------------------------------------
// Distance + reduce tile body. 128-row block tile, 4 waves (2x2); each wave
// owns 64 rows x 64 cols per column group, loops over G = CT*4 16-col groups.
// b[3][4]: depth-2 rolling B prefetch. acc[2][4]: double-buffered accumulator
// so the fmin/fmax epilogue of group g-1 overlaps the MFMA issue of group g.
// MFMA C seeded with ny; A pre-scaled by -2 => MFMA output IS (ny - 2 a.y).
// |a|^2 added once at the end (clamp at 0 commutes with min/max).
// MODE 0: per-row max -> atomicMax(dposBits[row]); MODE 1: global min ->
// one atomicMin(dnegBits) per block. No fences anywhere — all cross-block
// communication is via device-scope atomics (coherent on their own; a
// __threadfence here costs an L2 invalidate per block = 3x slowdown, R4).
// ---------------------------------------------------------------------------
template<int MODE, int CT>
__device__ __forceinline__ void dist_tile(
    const bf16x8* __restrict__ Af, const bf16x8* __restrict__ Yf,
    const float* __restrict__ nA, const float* __restrict__ nY,
    int by, int bx,
    unsigned* __restrict__ dposBits, unsigned* __restrict__ dnegBits)
{
    const int wid  = threadIdx.x >> 6;
    const int lane = threadIdx.x & 63;
    const int lm = lane & 15, lk = lane >> 4;
    const int wr = wid >> 1, wc = wid & 1;
    const int rt0 = by * 8 + wr * 4;          // first 16-row A tile of this wave

    // A fragments (pre-scaled by -2): 64 rows x 128 dims, resident throughout.
    bf16x8 a[4][4];
    #pragma unroll
    for (int m = 0; m < 4; ++m)
        #pragma unroll
        for (int s = 0; s < 4; ++s)
            a[m][s] = Af[(size_t)((rt0 + m) * 4 + s) * 64 + lane];

    float red[4][4];
    #pragma unroll
    for (int m = 0; m < 4; ++m)
        #pragma unroll
        for (int r = 0; r < 4; ++r)
            red[m][r] = (MODE == 0) ? -3.4e38f : 3.4e38f;

    constexpr int G = CT * 4;

    bf16x8 b[3][4];
    float nyv[3];
    #pragma unroll
    for (int p = 0; p < 2 && p < G; ++p) {
        const int ctile = (bx * CT + (p >> 2)) * 8 + wc * 4 + (p & 3);
        #pragma unroll
        for (int s = 0; s < 4; ++s)
            b[p][s] = Yf[(size_t)(ctile * 4 + s) * 64 + lane];
        nyv[p] = nY[ctile * 16 + lm];
    }

    f32x4 acc[2][4];

    #pragma unroll
    for (int g = 0; g < G; ++g) {
        const int cb = g % 3;      // current b buffer   (static after unroll)
        const int ab = g & 1;      // current acc buffer (static after unroll)
        // prefetch group g+2
        if (g + 2 < G) {
            const int ctile = (bx * CT + ((g + 2) >> 2)) * 8 + wc * 4 + ((g + 2) & 3);
            #pragma unroll
            for (int s = 0; s < 4; ++s)
                b[(g + 2) % 3][s] = Yf[(size_t)(ctile * 4 + s) * 64 + lane];
            nyv[(g + 2) % 3] = nY[ctile * 16 + lm];
        }
        // seed C with ny (off the dependent path), then MFMA
        const float ny = nyv[cb];
        #pragma unroll
        for (int m = 0; m < 4; ++m) acc[ab][m] = f32x4{ny, ny, ny, ny};
        #pragma unroll
        for (int s = 0; s < 4; ++s)
            #pragma unroll
            for (int m = 0; m < 4; ++m)
                acc[ab][m] = __builtin_amdgcn_mfma_f32_16x16x32_bf16(a[m][s], b[cb][s], acc[ab][m], 0, 0, 0);
        // epilogue of the PREVIOUS group overlaps this group's MFMAs
        if (g > 0) {
            #pragma unroll
            for (int m = 0; m < 4; ++m)
                #pragma unroll
                for (int r = 0; r < 4; ++r)
                    red[m][r] = (MODE == 0) ? fmaxf(red[m][r], acc[ab ^ 1][m][r])
                                            : fminf(red[m][r], acc[ab ^ 1][m][r]);
        }
    }
    // drain: epilogue of the last group
    {
        const int ab = (G - 1) & 1;
        #pragma unroll
        for (int m = 0; m < 4; ++m)
            #pragma unroll
            for (int r = 0; r < 4; ++r)
                red[m][r] = (MODE == 0) ? fmaxf(red[m][r], acc[ab][m][r])
                                        : fminf(red[m][r], acc[ab][m][r]);
    }

    float na[4][4];
    #pragma unroll
    for (int m = 0; m < 4; ++m)
        #pragma unroll
        for (int r = 0; r < 4; ++r)
            na[m][r] = nA[(rt0 + m) * 16 + 4 * lk + r];

    if (MODE == 0) {
        #pragma unroll
        for (int msk = 1; msk < 16; msk <<= 1)
            #pragma unroll
            for (int m = 0; m < 4; ++m)
                #pragma unroll
                for (int r = 0; r < 4; ++r)
                    red[m][r] = fmaxf(red[m][r], __shfl_xor(red[m][r], msk));
        if (lm == 0) {
            #pragma unroll
            for (int m = 0; m < 4; ++m)
                #pragma unroll
                for (int r = 0; r < 4; ++r) {
                    const float sq = fmaxf(na[m][r] + red[m][r], 0.f);
                    atomicMax(dposBits + ((rt0 + m) * 16 + 4 * lk + r),
                              __float_as_uint(sq));
                }
        }
    } else {
        float mn = 3.4e38f;
        #pragma unroll
        for (int m = 0; m < 4; ++m)
            #pragma unroll
            for (int r = 0; r < 4; ++r)
                mn = fminf(mn, na[m][r] + red[m][r]);
        mn = fmaxf(mn, 0.f);
        #pragma unroll
        for (int msk = 1; msk < 64; msk <<= 1) mn = fminf(mn, __shfl_xor(mn, msk));
        __shared__ float wmin[4];
        if (lane == 0) wmin[wid] = mn;
        __syncthreads();
        if (threadIdx.x == 0) {
            const float m2 = fminf(fminf(wmin[0], wmin[1]), fminf(wmin[2], wmin[3]));
            atomicMin(dnegBits, __float_as_uint(m2));
        }
    }
}

#define POS_BLOCKS ((P_POS / 128) * (B_ANCH / 128))            // 256
#define NEG_CT 8
#define NEG_BLOCKS ((N_NEG / (128 * NEG_CT)) * (B_ANCH / 128)) // 512
#define TOT_BLOCKS (POS_BLOCKS + NEG_BLOCKS)

__global__ __launch_bounds__(256, 2) void fused_dist_kernel(
    const short* __restrict__ pA, const short* __restrict__ pP,
    const short* __restrict__ pN,
    const float* __restrict__ nA, const float* __restrict__ nP,
    const float* __restrict__ nN,
    unsigned* __restrict__ dposBits, unsigned* __restrict__ dnegBits)
{
    const int bid = blockIdx.x;
    if (bid < POS_BLOCKS) {
        // positives: short blocks first so they co-schedule with negatives
        dist_tile<0, 1>((const bf16x8*)pA, (const bf16x8*)pP, nA, nP,
                        bid >> 4, bid & 15, dposBits, dnegBits);
    } else {
        const int q = bid - POS_BLOCKS;
        dist_tile<1, NEG_CT>((const bf16x8*)pA, (const bf16x8*)pN, nA, nN,
                             q >> 5, q & 31, dposBits, dnegBits);
    }
}

// ---------------------------------------------------------------------------
// Finalize: mean(relu(sqrt(dpos_sq) - sqrt(dneg_sq) + margin))
// ---------------------------------------------------------------------------
__global__ __launch_bounds__(256) void finalize_kernel(
    const unsigned* __restrict__ dposBits, const unsigned* __restrict__ dnegBits,
    float* __restrict__ out)
{
    const float dneg = sqrtf(__uint_as_float(*dnegBits));
    float s = 0.f;
    for (int i = threadIdx.x; i < B_ANCH; i += 256) {
        float dp = sqrtf(__uint_as_float(dposBits[i]));
        s += fmaxf(dp - dneg + MARGIN_F, 0.f);
    }
    #pragma unroll
    for (int m = 1; m < 64; m <<= 1) s += __shfl_xor(s, m);
    __shared__ float ws[4];
    const int wid = threadIdx.x >> 6, lane = threadIdx.x & 63;
    if (lane == 0) ws[wid] = s;
    __syncthreads();
    if (threadIdx.x == 0)
        out[0] = (ws[0] + ws[1] + ws[2] + ws[3]) * (1.f / (float)B_ANCH);
}

// ---------------------------------------------------------------------------
extern "C" void kernel_launch(void* const* d_in, const int* in_sizes, int n_in,
                              void* d_out, int out_size, void* d_ws, size_t ws_size,
                              hipStream_t stream) {
    const float* anchor   = (const float*)d_in[0];
    const float* positive = (const float*)d_in[1];
    const float* negative = (const float*)d_in[2];
    float* out = (float*)d_out;

    char* ws = (char*)d_ws;
    size_t off = 0;
    auto alloc = [&](size_t bytes) { char* p = ws + off; off = (off + bytes + 255) & ~(size_t)255; return p; };

    short* pA = (short*)alloc((size_t)B_ANCH * DDIM * 2);
    short* pP = (short*)alloc((size_t)P_POS  * DDIM * 2);
    short* pN = (short*)alloc((size_t)N_NEG  * DDIM * 2);
    float* nA  = (float*)alloc((size_t)B_ANCH * 4);
    float* nP  = (float*)alloc((size_t)P_POS  * 4);
    float* nN  = (float*)alloc((size_t)N_NEG  * 4);
    unsigned* dposBits = (unsigned*)alloc((size_t)B_ANCH * 4);
    unsigned* dnegBits = (unsigned*)alloc(4);

    // 1. prep: one wave per 16-row tile, 4 tiles per block
    const int totalTiles = (B_ANCH + P_POS + N_NEG) / 16;   // 2304
    prep_kernel<<<totalTiles / 4, 256, 0, stream>>>(
        anchor, positive, negative, pA, pP, pN, nA, nP, nN, dposBits, dnegBits);

    // 2. fused positives + negatives distance/reduce
    fused_dist_kernel<<<TOT_BLOCKS, 256, 0, stream>>>(
        pA, pP, pN, nA, nP, nN, dposBits, dnegBits);

    // 3. finalize
    finalize_kernel<<<1, 256, 0, stream>>>(dposBits, dnegBits, out);
}